// Round 6
// baseline (8299.039 us; speedup 1.0000x reference)
//
#include <hip/hip_runtime.h>

#define TSTEPS 20
constexpr float THRES = 1.0f;
constexpr float DECAY = 0.875f;  // (2^3-1)/2^3

constexpr int DIM_IN = 64;
constexpr int NIN = DIM_IN * DIM_IN;          // 4096
constexpr int C1 = 64, K1 = 7, D1 = 58;
constexpr int N1 = C1 * D1 * D1;              // 215296
constexpr int C2 = 128, K2 = 7, D2 = 52;
constexpr int N2 = C2 * D2 * D2;              // 346112
constexpr int NFLAT = N2;
constexpr int NHID = 512;
constexpr int NOUT = 10;
constexpr int KC = 8;           // conv2 K-split chunks
constexpr int CPC = C1 / KC;    // 8 input channels per chunk

// mega1 block roles: [0,512) gather | [512,928) conv2-partial | 928 misc
constexpr int NB_GATHER = 512;
constexpr int NB_PART = KC * 4 * 13;           // 416: (kc, cotg, yt)
constexpr int NB1 = NB_GATHER + NB_PART + 1;   // 929
// mega2 block roles: [0,1352) reduce | [1352,1416) conv1 | [1416,1424) finish
constexpr int NB_RED = N2 / 256;               // 1352
constexpr int NB_FIN = 8;
constexpr int NB2 = NB_RED + C1 + NB_FIN;      // 1424

// Persistent state (zeroed every kernel_launch; harness doesn't re-poison).
__device__ float g_mp_in[NIN];
__device__ float g_s_in[NIN];
__device__ float g_mp_c1[N1];
__device__ float g_sp_c1[2][N1];   // double-buffered by step parity
__device__ float g_mp_c2[N2];
__device__ float g_sp_c2[N2];      // dense fallback path only
__device__ float g_mp_l1[NHID];
__device__ float g_sp_l1[NHID];
__device__ float g_mp_l2[NOUT];
__device__ float g_dot[NHID];               // dense-fallback dot
__device__ float g_dotp[NB_GATHER][NHID];   // per-block gather partials (1 MB)
__device__ int   g_nnz[2];         // double-buffered spike counts
__device__ int   g_list[2][N2];    // double-buffered spike index lists

__global__ void init_kernel(float* __restrict__ out) {
    int i = blockIdx.x * blockDim.x + threadIdx.x;
    int stride = gridDim.x * blockDim.x;
    for (int j = i; j < NIN; j += stride) { g_mp_in[j] = 0.f; g_s_in[j] = 0.f; }
    for (int j = i; j < N1; j += stride) {
        g_mp_c1[j] = 0.f; g_sp_c1[0][j] = 0.f; g_sp_c1[1][j] = 0.f;
    }
    for (int j = i; j < N2; j += stride) { g_mp_c2[j] = 0.f; g_sp_c2[j] = 0.f; }
    if (i < NHID) { g_mp_l1[i] = 0.f; g_sp_l1[i] = 0.f; g_dot[i] = 0.f; }
    if (i < NOUT) g_mp_l2[i] = 0.f;
    if (i < (TSTEPS + 1) * NOUT) out[i] = 0.f;
    if (i < 2) g_nnz[i] = 0;
}

// One-time: w_l1 [512][NFLAT] -> wT [NFLAT][512]. 64x64 tiles.
__global__ void __launch_bounds__(256) transpose_kernel(const float* __restrict__ w,
                                                        float* __restrict__ wT) {
    __shared__ float tile[64][65];
    int bx = blockIdx.x * 64;
    int by = blockIdx.y * 64;
    int tx = threadIdx.x & 63, ty = threadIdx.x >> 6;
#pragma unroll
    for (int k = 0; k < 16; ++k)
        tile[ty + 4 * k][tx] = w[(size_t)(by + ty + 4 * k) * NFLAT + bx + tx];
    __syncthreads();
#pragma unroll
    for (int k = 0; k < 16; ++k)
        wT[(size_t)(bx + ty + 4 * k) * NHID + by + tx] = tile[tx][ty + 4 * k];
}

// ---- D1(t): gather(t) || conv2_partial(t) || {input(t), linear2(t), reset} ----
// All roles read only state produced at step t-1 (or earlier).
__global__ void __launch_bounds__(256, 8) mega1(const float* __restrict__ w2,
                                                const float* __restrict__ wT,
                                                const float* __restrict__ wl2,
                                                const float* __restrict__ image,
                                                float* __restrict__ part,
                                                float* __restrict__ out,
                                                int t, int sparse) {
    __shared__ float spk[CPC][10][58];  // 18.56 KB, block-shared (partial role)
    int bid = blockIdx.x, tid = threadIdx.x;
    int wid = tid >> 6, lane = tid & 63;

    if (bid < NB_GATHER) {
        // ---- linear1 sparse gather: per-block partial sums, NO atomics ----
        if (!sparse || t < 3 || t > 18) return;
        int p = (t + 1) & 1;               // parity of step t-1
        int nnz = g_nnz[p];
        const int* __restrict__ list = g_list[p];
        const float2* __restrict__ wT2 = (const float2*)wT;
        int h = tid;
        float2 a0 = {0.f,0.f}, a1 = {0.f,0.f}, a2 = {0.f,0.f}, a3 = {0.f,0.f};
        int i = bid;
        for (; i + 3 * NB_GATHER < nnz; i += 4 * NB_GATHER) {
            int j0 = list[i];
            int j1 = list[i + NB_GATHER];
            int j2 = list[i + 2 * NB_GATHER];
            int j3 = list[i + 3 * NB_GATHER];
            float2 w0 = wT2[(size_t)j0 * 256 + h];
            float2 w1v = wT2[(size_t)j1 * 256 + h];
            float2 w2v = wT2[(size_t)j2 * 256 + h];
            float2 w3 = wT2[(size_t)j3 * 256 + h];
            a0.x += w0.x; a0.y += w0.y;
            a1.x += w1v.x; a1.y += w1v.y;
            a2.x += w2v.x; a2.y += w2v.y;
            a3.x += w3.x; a3.y += w3.y;
        }
        for (; i < nnz; i += NB_GATHER) {
            float2 w0 = wT2[(size_t)list[i] * 256 + h];
            a0.x += w0.x; a0.y += w0.y;
        }
        float2 r;
        r.x = a0.x + a1.x + a2.x + a3.x;
        r.y = a0.y + a1.y + a2.y + a3.y;
        *(float2*)&g_dotp[bid][2 * h] = r;  // coalesced, deterministic
    } else if (bid < NB_GATHER + NB_PART) {
        // ---- conv2 partial: block-shared spike tile, wave = co-group ----
        if (t < 2 || t > 17) return;
        int pb = bid - NB_GATHER;          // 0..415
        int kc = pb & 7;
        int tmp = pb >> 3;
        int cotg = tmp & 3;
        int yt = tmp >> 2;                 // 0..12
        int c0 = kc * CPC, y0 = yt * 4;
        const float* __restrict__ sp = g_sp_c1[(t + 1) & 1];  // step t-1 spikes
        for (int e = tid; e < CPC * 10 * 58; e += 256) {
            int c = e / 580, rem = e - c * 580;
            int r = rem / 58, x = rem - r * 58;
            spk[c][r][x] = sp[(c0 + c) * (D1 * D1) + (y0 + r) * D1 + x];
        }
        __syncthreads();
        int co0 = (cotg * 4 + wid) * 8;    // this wave's 8 output channels
        float acc[8][4] = {};
        bool act = lane < D2;
#pragma unroll 1
        for (int c = 0; c < CPC; ++c) {
#pragma unroll
            for (int ky = 0; ky < K2; ++ky) {
                float wv[8][7];  // wave-uniform -> scalar loads
#pragma unroll
                for (int cl = 0; cl < 8; ++cl)
#pragma unroll
                    for (int kx = 0; kx < 7; ++kx)
                        wv[cl][kx] = w2[((size_t)(co0 + cl) * C1 + c0 + c) * 49 + ky * 7 + kx];
                if (act) {
#pragma unroll
                    for (int o = 0; o < 4; ++o) {
                        float v[7];
#pragma unroll
                        for (int kx = 0; kx < 7; ++kx) v[kx] = spk[c][o + ky][lane + kx];
#pragma unroll
                        for (int kx = 0; kx < 7; ++kx)
#pragma unroll
                            for (int cl = 0; cl < 8; ++cl)
                                acc[cl][o] = fmaf(v[kx], wv[cl][kx], acc[cl][o]);
                    }
                }
            }
        }
        if (act) {
#pragma unroll
            for (int cl = 0; cl < 8; ++cl)
#pragma unroll
                for (int o = 0; o < 4; ++o)
                    part[(size_t)kc * N2 + (co0 + cl) * (D2 * D2) + (y0 + o) * D2 + lane] =
                        acc[cl][o];
        }
    } else {
        // ---- misc: nnz reset, input integrate/fire, linear2 ----
        if (tid == 0) g_nnz[t & 1] = 0;    // before reduce(t) increments in D2(t)
        if (t <= 16) {
            for (int j = tid; j < NIN; j += 256) {
                float mp = g_mp_in[j] + image[j];
                float f = (mp >= THRES) ? 1.f : 0.f;
                g_s_in[j] = f;
                g_mp_in[j] = mp - THRES * f;   // SnnInput: no decay
            }
        }
        if (t >= 4) {
            for (int o = wid; o < NOUT; o += 4) {
                float a = 0.f;
#pragma unroll
                for (int k = lane; k < NHID; k += 64)
                    a = fmaf(wl2[o * NHID + k], g_sp_l1[k], a);  // sp_l1 from t-1
                for (int off = 32; off; off >>= 1) a += __shfl_down(a, off, 64);
                if (lane == 0) {
                    float mp = g_mp_l2[o] * DECAY + a;
                    float f = (mp >= THRES) ? 1.f : 0.f;
                    g_mp_l2[o] = mp - THRES * f;
                    out[(t + 1) * NOUT + o] = f;
                }
            }
        }
    }
}

// ---- D2(t): conv2_reduce(t) || conv1(t) || linear1_finish(t) ----
__global__ void __launch_bounds__(256, 8) mega2(const float* __restrict__ w1,
                                                const float* __restrict__ part,
                                                int t, int sparse) {
    __shared__ float sim[NIN];  // 16 KB (conv1 role; finish reuses first 256)
    int bid = blockIdx.x, tid = threadIdx.x;

    if (bid < NB_RED) {
        // ---- conv2 reduce: deterministic KC-sum, fire, decay, spike list ----
        if (t < 2 || t > 17) return;
        int i = bid * 256 + tid;
        float s = 0.f;
#pragma unroll
        for (int k = 0; k < KC; ++k) s += part[(size_t)k * N2 + i];
        float mp = g_mp_c2[i] + s;
        float f = (mp >= THRES) ? 1.f : 0.f;
        g_mp_c2[i] = (mp - THRES * f) * ((f > 0.f) ? 1.f : DECAY);
        if (!sparse) g_sp_c2[i] = f;
        if (f > 0.f) {
            int pos = atomicAdd(&g_nnz[t & 1], 1);
            g_list[t & 1][pos] = i;
        }
    } else if (bid < NB_RED + C1) {
        // ---- conv1: whole spike image in LDS, uniform weights ----
        if (t < 1 || t > 16) return;
        int co = bid - NB_RED;
        const float4* __restrict__ s4 = (const float4*)g_s_in;
        float4* d4 = (float4*)sim;
        for (int j = tid; j < NIN / 4; j += 256) d4[j] = s4[j];
        __syncthreads();
        float w[49];
#pragma unroll
        for (int k = 0; k < 49; ++k) w[k] = w1[co * 49 + k];
        float* __restrict__ spb = g_sp_c1[t & 1];
        for (int idx = tid; idx < D1 * D1; idx += 256) {
            int y = idx / D1, x = idx - y * D1;
            float a = 0.f;
#pragma unroll
            for (int ky = 0; ky < K1; ++ky)
#pragma unroll
                for (int kx = 0; kx < K1; ++kx)
                    a = fmaf(sim[(y + ky) * DIM_IN + x + kx], w[ky * K1 + kx], a);
            int o = co * (D1 * D1) + idx;
            float mp = g_mp_c1[o] + a;
            float f = (mp >= THRES) ? 1.f : 0.f;
            g_mp_c1[o] = (mp - THRES * f) * ((f > 0.f) ? 1.f : DECAY);
            spb[o] = f;
        }
    } else {
        // ---- linear1 finish: fixed-order reduction of gather partials ----
        if (t < 3 || t > 18) return;
        int fb = bid - NB_RED - C1;        // 0..7
        int hl = tid & 63, w = tid >> 6;   // 64 h per block, 4 b-chunks
        int h = fb * 64 + hl;
        float tot;
        if (sparse) {
            float s = 0.f;
            int b0 = w * (NB_GATHER / 4);
#pragma unroll 8
            for (int b = b0; b < b0 + NB_GATHER / 4; ++b) s += g_dotp[b][h];
            sim[w * 64 + hl] = s;
            __syncthreads();
            if (w != 0) return;
            tot = ((sim[hl] + sim[64 + hl]) + sim[128 + hl]) + sim[192 + hl];
        } else {
            if (w != 0) return;
            tot = g_dot[h];
        }
        float mp = g_mp_l1[h] * DECAY + tot;
        float f = (mp >= THRES) ? 1.f : 0.f;
        g_mp_l1[h] = mp - THRES * f;
        g_sp_l1[h] = f;
    }
}

// Dense fallback (ws too small for wT): writes g_dot[row]; finish applies it.
__global__ void __launch_bounds__(256) linear1_dense(const float* __restrict__ wl1) {
    int row = blockIdx.x;
    const float4* __restrict__ w4 = (const float4*)(wl1 + (size_t)row * NFLAT);
    const float4* __restrict__ s4 = (const float4*)g_sp_c2;
    float acc = 0.f;
    for (int j = threadIdx.x; j < NFLAT / 4; j += 256) {
        float4 w = w4[j];
        float4 s = s4[j];
        acc += w.x * s.x + w.y * s.y + w.z * s.z + w.w * s.w;
    }
    __shared__ float red[256];
    red[threadIdx.x] = acc;
    __syncthreads();
    for (int off = 128; off >= 1; off >>= 1) {
        if (threadIdx.x < off) red[threadIdx.x] += red[threadIdx.x + off];
        __syncthreads();
    }
    if (threadIdx.x == 0) g_dot[row] = red[0];
}

extern "C" void kernel_launch(void* const* d_in, const int* in_sizes, int n_in,
                              void* d_out, int out_size, void* d_ws, size_t ws_size,
                              hipStream_t stream) {
    const float* image = (const float*)d_in[0];
    const float* w_c1 = (const float*)d_in[1];
    const float* w_c2 = (const float*)d_in[2];
    const float* w_l1 = (const float*)d_in[3];
    const float* w_l2 = (const float*)d_in[4];
    float* out = (float*)d_out;

    float* wT = (float*)d_ws;
    size_t wt_elems = (size_t)NFLAT * NHID;
    size_t part_elems = (size_t)KC * N2;
    bool sparse = ws_size >= (wt_elems + part_elems) * sizeof(float);
    float* part = sparse ? wT + wt_elems : (float*)d_ws;

    init_kernel<<<512, 256, 0, stream>>>(out);
    if (sparse)
        transpose_kernel<<<dim3(NFLAT / 64, NHID / 64), 256, 0, stream>>>(w_l1, wT);

    // Live ranges: input 0..16, conv1 1..16, conv2 2..17, l1 3..18, l2 4..19.
    for (int t = 0; t < TSTEPS; ++t) {
        if (!sparse && t >= 3 && t <= 18)
            linear1_dense<<<NHID, 256, 0, stream>>>(w_l1);
        mega1<<<NB1, 256, 0, stream>>>(w_c2, wT, w_l2, image, part, out, t,
                                       sparse ? 1 : 0);
        if (t >= 1 && t <= 18)
            mega2<<<NB2, 256, 0, stream>>>(w_c1, part, t, sparse ? 1 : 0);
    }
}

// Round 7
// 2736.001 us; speedup vs baseline: 3.0333x; 3.0333x over previous
//
#include <hip/hip_runtime.h>

#define TSTEPS 20
constexpr float THRES = 1.0f;
constexpr float DECAY = 0.875f;  // (2^3-1)/2^3

constexpr int DIM_IN = 64;
constexpr int NIN = DIM_IN * DIM_IN;          // 4096
constexpr int C1 = 64, K1 = 7, D1 = 58;
constexpr int N1 = C1 * D1 * D1;              // 215296
constexpr int C2 = 128, K2 = 7, D2 = 52;
constexpr int N2 = C2 * D2 * D2;              // 346112
constexpr int NFLAT = N2;
constexpr int NHID = 512;
constexpr int NOUT = 10;
constexpr int KC = 8;           // conv2 K-split chunks
constexpr int CPC = C1 / KC;    // 8 input channels per chunk

// mega1 block roles: [0,512) gather | [512,928) conv2-partial | 928 misc
constexpr int NB_GATHER = 512;
constexpr int NB_PART = KC * 4 * 13;           // 416: (kc, cotg, yt)
constexpr int NB1 = NB_GATHER + NB_PART + 1;   // 929
// mega2 block roles: [0,1352) reduce | [1352,1416) conv1 | [1416,1424) finish
constexpr int NB_RED = N2 / 256;               // 1352
constexpr int NB_FIN = 8;
constexpr int NB2 = NB_RED + C1 + NB_FIN;      // 1424

// Persistent state (zeroed every kernel_launch; harness doesn't re-poison).
__device__ float g_mp_in[NIN];
__device__ float g_s_in[NIN];
__device__ float g_mp_c1[N1];
__device__ float g_sp_c1[2][N1];   // double-buffered by step parity
__device__ float g_mp_c2[N2];
__device__ float g_sp_c2[N2];      // dense fallback path only
__device__ float g_mp_l1[NHID];
__device__ float g_sp_l1[NHID];
__device__ float g_mp_l2[NOUT];
__device__ float g_dot[NHID];               // dense-fallback dot
__device__ float g_dotp[NB_GATHER][NHID];   // per-block gather partials (1 MB)
__device__ int   g_nnz[2];         // double-buffered spike counts
__device__ int   g_list[2][N2];    // double-buffered spike index lists

__global__ void init_kernel(float* __restrict__ out) {
    int i = blockIdx.x * blockDim.x + threadIdx.x;
    int stride = gridDim.x * blockDim.x;
    for (int j = i; j < NIN; j += stride) { g_mp_in[j] = 0.f; g_s_in[j] = 0.f; }
    for (int j = i; j < N1; j += stride) {
        g_mp_c1[j] = 0.f; g_sp_c1[0][j] = 0.f; g_sp_c1[1][j] = 0.f;
    }
    for (int j = i; j < N2; j += stride) { g_mp_c2[j] = 0.f; g_sp_c2[j] = 0.f; }
    if (i < NHID) { g_mp_l1[i] = 0.f; g_sp_l1[i] = 0.f; g_dot[i] = 0.f; }
    if (i < NOUT) g_mp_l2[i] = 0.f;
    if (i < (TSTEPS + 1) * NOUT) out[i] = 0.f;
    if (i < 2) g_nnz[i] = 0;
}

// One-time: w_l1 [512][NFLAT] -> wT [NFLAT][512]. 64x64 tiles.
__global__ void __launch_bounds__(256) transpose_kernel(const float* __restrict__ w,
                                                        float* __restrict__ wT) {
    __shared__ float tile[64][65];
    int bx = blockIdx.x * 64;
    int by = blockIdx.y * 64;
    int tx = threadIdx.x & 63, ty = threadIdx.x >> 6;
#pragma unroll
    for (int k = 0; k < 16; ++k)
        tile[ty + 4 * k][tx] = w[(size_t)(by + ty + 4 * k) * NFLAT + bx + tx];
    __syncthreads();
#pragma unroll
    for (int k = 0; k < 16; ++k)
        wT[(size_t)(bx + ty + 4 * k) * NHID + by + tx] = tile[tx][ty + 4 * k];
}

// ---- D1(t): gather(t) || conv2_partial(t) || {input(t), linear2(t), reset} ----
// All roles read only state produced at step t-1 (or earlier).
// NOTE: no min-waves in launch_bounds — round 6's ",8" capped VGPRs at 32 and
// conv2-partial spilled ~320 MB/dispatch to scratch (463 us/dispatch).
__global__ void __launch_bounds__(256) mega1(const float* __restrict__ w2,
                                             const float* __restrict__ wT,
                                             const float* __restrict__ wl2,
                                             const float* __restrict__ image,
                                             float* __restrict__ part,
                                             float* __restrict__ out,
                                             int t, int sparse) {
    __shared__ float spk[CPC][10][58];  // 18.56 KB, block-shared (partial role)
    int bid = blockIdx.x, tid = threadIdx.x;
    int wid = tid >> 6, lane = tid & 63;

    if (bid < NB_GATHER) {
        // ---- linear1 sparse gather: per-block partial sums, NO atomics ----
        if (!sparse || t < 3 || t > 18) return;
        int p = (t + 1) & 1;               // parity of step t-1
        int nnz = g_nnz[p];
        const int* __restrict__ list = g_list[p];
        const float2* __restrict__ wT2 = (const float2*)wT;
        int h = tid;
        float2 a0 = {0.f,0.f}, a1 = {0.f,0.f}, a2 = {0.f,0.f}, a3 = {0.f,0.f};
        int i = bid;
        for (; i + 3 * NB_GATHER < nnz; i += 4 * NB_GATHER) {
            int j0 = list[i];
            int j1 = list[i + NB_GATHER];
            int j2 = list[i + 2 * NB_GATHER];
            int j3 = list[i + 3 * NB_GATHER];
            float2 w0 = wT2[(size_t)j0 * 256 + h];
            float2 w1v = wT2[(size_t)j1 * 256 + h];
            float2 w2v = wT2[(size_t)j2 * 256 + h];
            float2 w3 = wT2[(size_t)j3 * 256 + h];
            a0.x += w0.x; a0.y += w0.y;
            a1.x += w1v.x; a1.y += w1v.y;
            a2.x += w2v.x; a2.y += w2v.y;
            a3.x += w3.x; a3.y += w3.y;
        }
        for (; i < nnz; i += NB_GATHER) {
            float2 w0 = wT2[(size_t)list[i] * 256 + h];
            a0.x += w0.x; a0.y += w0.y;
        }
        float2 r;
        r.x = a0.x + a1.x + a2.x + a3.x;
        r.y = a0.y + a1.y + a2.y + a3.y;
        *(float2*)&g_dotp[bid][2 * h] = r;  // coalesced, deterministic
    } else if (bid < NB_GATHER + NB_PART) {
        // ---- conv2 partial: block-shared spike tile, wave = co-group ----
        if (t < 2 || t > 17) return;
        int pb = bid - NB_GATHER;          // 0..415
        int kc = pb & 7;
        int tmp = pb >> 3;
        int cotg = tmp & 3;
        int yt = tmp >> 2;                 // 0..12
        int c0 = kc * CPC, y0 = yt * 4;
        const float* __restrict__ sp = g_sp_c1[(t + 1) & 1];  // step t-1 spikes
        for (int e = tid; e < CPC * 10 * 58; e += 256) {
            int c = e / 580, rem = e - c * 580;
            int r = rem / 58, x = rem - r * 58;
            spk[c][r][x] = sp[(c0 + c) * (D1 * D1) + (y0 + r) * D1 + x];
        }
        __syncthreads();
        int co0 = (cotg * 4 + wid) * 8;    // this wave's 8 output channels
        float acc[8][4] = {};
        bool act = lane < D2;
#pragma unroll 1
        for (int c = 0; c < CPC; ++c) {
#pragma unroll
            for (int ky = 0; ky < K2; ++ky) {
                float wv[8][7];  // wave-uniform -> scalar loads
#pragma unroll
                for (int cl = 0; cl < 8; ++cl)
#pragma unroll
                    for (int kx = 0; kx < 7; ++kx)
                        wv[cl][kx] = w2[((size_t)(co0 + cl) * C1 + c0 + c) * 49 + ky * 7 + kx];
                if (act) {
#pragma unroll
                    for (int o = 0; o < 4; ++o) {
                        float v[7];
#pragma unroll
                        for (int kx = 0; kx < 7; ++kx) v[kx] = spk[c][o + ky][lane + kx];
#pragma unroll
                        for (int kx = 0; kx < 7; ++kx)
#pragma unroll
                            for (int cl = 0; cl < 8; ++cl)
                                acc[cl][o] = fmaf(v[kx], wv[cl][kx], acc[cl][o]);
                    }
                }
            }
        }
        if (act) {
#pragma unroll
            for (int cl = 0; cl < 8; ++cl)
#pragma unroll
                for (int o = 0; o < 4; ++o)
                    part[(size_t)kc * N2 + (co0 + cl) * (D2 * D2) + (y0 + o) * D2 + lane] =
                        acc[cl][o];
        }
    } else {
        // ---- misc: nnz reset, input integrate/fire, linear2 ----
        if (tid == 0) g_nnz[t & 1] = 0;    // before reduce(t) increments in D2(t)
        if (t <= 16) {
            for (int j = tid; j < NIN; j += 256) {
                float mp = g_mp_in[j] + image[j];
                float f = (mp >= THRES) ? 1.f : 0.f;
                g_s_in[j] = f;
                g_mp_in[j] = mp - THRES * f;   // SnnInput: no decay
            }
        }
        if (t >= 4) {
            for (int o = wid; o < NOUT; o += 4) {
                float a = 0.f;
#pragma unroll
                for (int k = lane; k < NHID; k += 64)
                    a = fmaf(wl2[o * NHID + k], g_sp_l1[k], a);  // sp_l1 from t-1
                for (int off = 32; off; off >>= 1) a += __shfl_down(a, off, 64);
                if (lane == 0) {
                    float mp = g_mp_l2[o] * DECAY + a;
                    float f = (mp >= THRES) ? 1.f : 0.f;
                    g_mp_l2[o] = mp - THRES * f;
                    out[(t + 1) * NOUT + o] = f;
                }
            }
        }
    }
}

// ---- D2(t): conv2_reduce(t) || conv1(t) || linear1_finish(t) ----
__global__ void __launch_bounds__(256) mega2(const float* __restrict__ w1,
                                             const float* __restrict__ part,
                                             int t, int sparse) {
    __shared__ float sim[NIN];  // 16 KB (conv1 role; finish reuses first 256)
    int bid = blockIdx.x, tid = threadIdx.x;

    if (bid < NB_RED) {
        // ---- conv2 reduce: deterministic KC-sum, fire, decay, spike list ----
        if (t < 2 || t > 17) return;
        int i = bid * 256 + tid;
        float s = 0.f;
#pragma unroll
        for (int k = 0; k < KC; ++k) s += part[(size_t)k * N2 + i];
        float mp = g_mp_c2[i] + s;
        float f = (mp >= THRES) ? 1.f : 0.f;
        g_mp_c2[i] = (mp - THRES * f) * ((f > 0.f) ? 1.f : DECAY);
        if (!sparse) g_sp_c2[i] = f;
        if (f > 0.f) {
            int pos = atomicAdd(&g_nnz[t & 1], 1);
            g_list[t & 1][pos] = i;
        }
    } else if (bid < NB_RED + C1) {
        // ---- conv1: whole spike image in LDS, uniform weights ----
        if (t < 1 || t > 16) return;
        int co = bid - NB_RED;
        const float4* __restrict__ s4 = (const float4*)g_s_in;
        float4* d4 = (float4*)sim;
        for (int j = tid; j < NIN / 4; j += 256) d4[j] = s4[j];
        __syncthreads();
        float w[49];
#pragma unroll
        for (int k = 0; k < 49; ++k) w[k] = w1[co * 49 + k];
        float* __restrict__ spb = g_sp_c1[t & 1];
        for (int idx = tid; idx < D1 * D1; idx += 256) {
            int y = idx / D1, x = idx - y * D1;
            float a = 0.f;
#pragma unroll
            for (int ky = 0; ky < K1; ++ky)
#pragma unroll
                for (int kx = 0; kx < K1; ++kx)
                    a = fmaf(sim[(y + ky) * DIM_IN + x + kx], w[ky * K1 + kx], a);
            int o = co * (D1 * D1) + idx;
            float mp = g_mp_c1[o] + a;
            float f = (mp >= THRES) ? 1.f : 0.f;
            g_mp_c1[o] = (mp - THRES * f) * ((f > 0.f) ? 1.f : DECAY);
            spb[o] = f;
        }
    } else {
        // ---- linear1 finish: fixed-order reduction of gather partials ----
        if (t < 3 || t > 18) return;
        int fb = bid - NB_RED - C1;        // 0..7
        int hl = tid & 63, w = tid >> 6;   // 64 h per block, 4 b-chunks
        int h = fb * 64 + hl;
        float tot;
        if (sparse) {
            float s = 0.f;
            int b0 = w * (NB_GATHER / 4);
#pragma unroll 8
            for (int b = b0; b < b0 + NB_GATHER / 4; ++b) s += g_dotp[b][h];
            sim[w * 64 + hl] = s;
            __syncthreads();
            if (w != 0) return;
            tot = ((sim[hl] + sim[64 + hl]) + sim[128 + hl]) + sim[192 + hl];
        } else {
            if (w != 0) return;
            tot = g_dot[h];
        }
        float mp = g_mp_l1[h] * DECAY + tot;
        float f = (mp >= THRES) ? 1.f : 0.f;
        g_mp_l1[h] = mp - THRES * f;
        g_sp_l1[h] = f;
    }
}

// Dense fallback (ws too small for wT): writes g_dot[row]; finish applies it.
__global__ void __launch_bounds__(256) linear1_dense(const float* __restrict__ wl1) {
    int row = blockIdx.x;
    const float4* __restrict__ w4 = (const float4*)(wl1 + (size_t)row * NFLAT);
    const float4* __restrict__ s4 = (const float4*)g_sp_c2;
    float acc = 0.f;
    for (int j = threadIdx.x; j < NFLAT / 4; j += 256) {
        float4 w = w4[j];
        float4 s = s4[j];
        acc += w.x * s.x + w.y * s.y + w.z * s.z + w.w * s.w;
    }
    __shared__ float red[256];
    red[threadIdx.x] = acc;
    __syncthreads();
    for (int off = 128; off >= 1; off >>= 1) {
        if (threadIdx.x < off) red[threadIdx.x] += red[threadIdx.x + off];
        __syncthreads();
    }
    if (threadIdx.x == 0) g_dot[row] = red[0];
}

extern "C" void kernel_launch(void* const* d_in, const int* in_sizes, int n_in,
                              void* d_out, int out_size, void* d_ws, size_t ws_size,
                              hipStream_t stream) {
    const float* image = (const float*)d_in[0];
    const float* w_c1 = (const float*)d_in[1];
    const float* w_c2 = (const float*)d_in[2];
    const float* w_l1 = (const float*)d_in[3];
    const float* w_l2 = (const float*)d_in[4];
    float* out = (float*)d_out;

    float* wT = (float*)d_ws;
    size_t wt_elems = (size_t)NFLAT * NHID;
    size_t part_elems = (size_t)KC * N2;
    bool sparse = ws_size >= (wt_elems + part_elems) * sizeof(float);
    float* part = sparse ? wT + wt_elems : (float*)d_ws;

    init_kernel<<<512, 256, 0, stream>>>(out);
    if (sparse)
        transpose_kernel<<<dim3(NFLAT / 64, NHID / 64), 256, 0, stream>>>(w_l1, wT);

    // Live ranges: input 0..16, conv1 1..16, conv2 2..17, l1 3..18, l2 4..19.
    for (int t = 0; t < TSTEPS; ++t) {
        if (!sparse && t >= 3 && t <= 18)
            linear1_dense<<<NHID, 256, 0, stream>>>(w_l1);
        mega1<<<NB1, 256, 0, stream>>>(w_c2, wT, w_l2, image, part, out, t,
                                       sparse ? 1 : 0);
        if (t >= 1 && t <= 18)
            mega2<<<NB2, 256, 0, stream>>>(w_c1, part, t, sparse ? 1 : 0);
    }
}

// Round 8
// 2239.718 us; speedup vs baseline: 3.7054x; 1.2216x over previous
//
#include <hip/hip_runtime.h>

#define TSTEPS 20
constexpr float THRES = 1.0f;
constexpr float DECAY = 0.875f;  // (2^3-1)/2^3

constexpr int DIM_IN = 64;
constexpr int NIN = DIM_IN * DIM_IN;          // 4096
constexpr int C1 = 64, K1 = 7, D1 = 58;
constexpr int N1 = C1 * D1 * D1;              // 215296
constexpr int C2 = 128, K2 = 7, D2 = 52;
constexpr int N2 = C2 * D2 * D2;              // 346112
constexpr int NFLAT = N2;
constexpr int NHID = 512;
constexpr int NOUT = 10;
constexpr int KC = 16;          // conv2 K-split chunks
constexpr int CPC = C1 / KC;    // 4 input channels per chunk
constexpr int W2R_ELEMS = 256 * 28 * 64;      // reshuffled conv2 weights

// mega1 roles: [0,832) partial | [832,1600) gather | [1600,1664) conv1 |
//              [1664,1672) finish(t-1) | 1672 misc
constexpr int NB_PARTIAL = KC * 13 * 4;        // 832: (kc, yt, cotg)
constexpr int NB_GATHER = 768;
constexpr int NB_CONV1 = C1;                   // 64
constexpr int NB_FIN = 8;
constexpr int NB1 = NB_PARTIAL + NB_GATHER + NB_CONV1 + NB_FIN + 1;  // 1673
// mega2 roles: [0,1352) reduce | 1352 input(t+1) | 1353 linear2(t)
constexpr int NB_RED = N2 / 256;               // 1352
constexpr int NB2 = NB_RED + 2;                // 1354

// Persistent state (re-initialized every kernel_launch).
__device__ float g_mp_in[NIN];
__device__ float g_s_in[NIN];
__device__ float g_mp_c1[N1];
__device__ float g_sp_c1[2][N1];   // double-buffered by step parity
__device__ float g_mp_c2[N2];
__device__ float g_sp_c2[N2];      // dense fallback path only
__device__ float g_mp_l1[NHID];
__device__ float g_sp_l1[NHID];
__device__ float g_mp_l2[NOUT];
__device__ float g_dot[NHID];                  // dense-fallback dot
__device__ double g_dotp[2][NB_GATHER][NHID];  // gather partials, fp64 (6.3 MB)
__device__ int   g_nnz[2];
__device__ int   g_list[2][N2];
__device__ float g_part[KC * N2];              // conv2 K-split partials (22 MB)
__device__ float g_w2r[W2R_ELEMS];             // reshuffled conv2 weights

// init: zero state; fold input(0) and input(1) (image-only, deterministic):
// t=0: mp=image<1 -> no fire; t=1: mp=2*image, fire f1.
__global__ void init_kernel(const float* __restrict__ image, float* __restrict__ out) {
    int i = blockIdx.x * blockDim.x + threadIdx.x;
    int stride = gridDim.x * blockDim.x;
    for (int j = i; j < NIN; j += stride) {
        float mp = 2.f * image[j];
        float f = (mp >= THRES) ? 1.f : 0.f;
        g_mp_in[j] = mp - THRES * f;
        g_s_in[j] = f;                 // s_in(1), read by conv1(1)
    }
    for (int j = i; j < N1; j += stride) {
        g_mp_c1[j] = 0.f; g_sp_c1[0][j] = 0.f; g_sp_c1[1][j] = 0.f;
    }
    for (int j = i; j < N2; j += stride) { g_mp_c2[j] = 0.f; g_sp_c2[j] = 0.f; }
    if (i < NHID) { g_mp_l1[i] = 0.f; g_sp_l1[i] = 0.f; g_dot[i] = 0.f; }
    if (i < NOUT) g_mp_l2[i] = 0.f;
    if (i < (TSTEPS + 1) * NOUT) out[i] = 0.f;
    if (i < 2) g_nnz[i] = 0;
}

// One-time: w_l1 [512][NFLAT] -> wT [NFLAT][512]. 64x64 tiles.
__global__ void __launch_bounds__(256) transpose_kernel(const float* __restrict__ w,
                                                        float* __restrict__ wT) {
    __shared__ float tile[64][65];
    int bx = blockIdx.x * 64;
    int by = blockIdx.y * 64;
    int tx = threadIdx.x & 63, ty = threadIdx.x >> 6;
#pragma unroll
    for (int k = 0; k < 16; ++k)
        tile[ty + 4 * k][tx] = w[(size_t)(by + ty + 4 * k) * NFLAT + bx + tx];
    __syncthreads();
#pragma unroll
    for (int k = 0; k < 16; ++k)
        wT[(size_t)(bx + ty + 4 * k) * NHID + by + tx] = tile[tx][ty + 4 * k];
}

// One-time: w_c2 [co][ci][ky][kx] -> w2r [(kc*16+cot)][c*7+ky][cl*8+kx] (kx pad 8)
__global__ void __launch_bounds__(256) reshuffle_w2(const float* __restrict__ w2) {
    int idx = blockIdx.x * 256 + threadIdx.x;
    if (idx >= C2 * C1 * 49) return;
    int co = idx / (C1 * 49);
    int rem = idx - co * (C1 * 49);
    int ci = rem / 49;
    int k = rem - ci * 49;
    int ky = k / 7, kx = k - ky * 7;
    int kc = ci >> 2, c = ci & 3;     // CPC = 4
    int cot = co >> 3, cl = co & 7;
    g_w2r[((size_t)(kc * 16 + cot) * 28 + (c * 7 + ky)) * 64 + cl * 8 + kx] = w2[idx];
}

// ---- D1(t): partial(t) || gather(t) || conv1(t) || finish(t-1) || misc ----
// Every role reads ONLY prior-dispatch state:
//   partial(t):  sp_c1[(t-1)&1]  (conv1(t-1), D1(t-1))
//   gather(t):   list/nnz[(t-1)&1] (reduce(t-1), D2(t-1))
//   conv1(t):    s_in(t)         (input role of D2(t-1), or init)
//   finish(t-1): dotp[(t-1)&1]   (gather(t-1), D1(t-1))
__global__ void __launch_bounds__(256) mega1(const float* __restrict__ w1,
                                             const float* __restrict__ wT,
                                             int t, int sparse) {
    __shared__ union __align__(16) {
        float spk[CPC][10][58];   // 9.28 KB (partial)
        float sim[NIN];           // 16 KB  (conv1)
        double fin[256];          // 2 KB   (finish)
    } sm;
    int bid = blockIdx.x, tid = threadIdx.x;
    int wid = tid >> 6, lane = tid & 63;

    if (bid < NB_PARTIAL) {
        // ---- conv2 partial: block tile (kc,yt), wave = co-group ----
        if (t < 2 || t > 17) return;
        int kc = bid & 15;
        int tmp = bid >> 4;            // 0..51
        int cotg = tmp & 3;
        int yt = tmp >> 2;             // 0..12
        int c0 = kc * CPC, y0 = yt * 4;
        const float* __restrict__ sp = g_sp_c1[(t + 1) & 1];
        for (int e = tid; e < CPC * 10 * 58; e += 256) {
            int c = e / 580, rem = e - c * 580;
            int r = rem / 58, x = rem - r * 58;
            sm.spk[c][r][x] = sp[(c0 + c) * (D1 * D1) + (y0 + r) * D1 + x];
        }
        __syncthreads();
        int cot = __builtin_amdgcn_readfirstlane(cotg * 4 + wid);
        int co0 = cot * 8;
        float acc[8][4] = {};
        bool act = lane < D2;
#pragma unroll 1
        for (int c = 0; c < CPC; ++c) {
#pragma unroll
            for (int ky = 0; ky < K2; ++ky) {
                // uniform address -> s_loads into SGPRs
                const float* __restrict__ wrow =
                    g_w2r + ((size_t)(kc * 16 + cot) * 28 + (c * 7 + ky)) * 64;
                float wv[8][7];
#pragma unroll
                for (int cl = 0; cl < 8; ++cl)
#pragma unroll
                    for (int kx = 0; kx < 7; ++kx) wv[cl][kx] = wrow[cl * 8 + kx];
                if (act) {
#pragma unroll
                    for (int o = 0; o < 4; ++o) {
                        float v[7];
#pragma unroll
                        for (int kx = 0; kx < 7; ++kx) v[kx] = sm.spk[c][o + ky][lane + kx];
#pragma unroll
                        for (int kx = 0; kx < 7; ++kx)
#pragma unroll
                            for (int cl = 0; cl < 8; ++cl)
                                acc[cl][o] = fmaf(v[kx], wv[cl][kx], acc[cl][o]);
                    }
                }
            }
        }
        if (act) {
#pragma unroll
            for (int cl = 0; cl < 8; ++cl)
#pragma unroll
                for (int o = 0; o < 4; ++o)
                    g_part[(size_t)kc * N2 + (co0 + cl) * (D2 * D2) + (y0 + o) * D2 + lane] =
                        acc[cl][o];
        }
    } else if (bid < NB_PARTIAL + NB_GATHER) {
        // ---- linear1 gather: fp64 per-block partials, 8-deep ILP ----
        if (!sparse || t < 3 || t > 18) return;
        int gb = bid - NB_PARTIAL;
        int p = (t + 1) & 1;
        int nnz = g_nnz[p];
        const int* __restrict__ list = g_list[p];
        const float2* __restrict__ wT2 = (const float2*)wT;
        int h = tid;
        double ax[8] = {}, ay[8] = {};
        int i = gb;
        for (; i + 7 * NB_GATHER < nnz; i += 8 * NB_GATHER) {
            int j[8];
#pragma unroll
            for (int u = 0; u < 8; ++u) j[u] = list[i + u * NB_GATHER];
#pragma unroll
            for (int u = 0; u < 8; ++u) {
                float2 w = wT2[(size_t)j[u] * 256 + h];
                ax[u] += w.x; ay[u] += w.y;
            }
        }
        for (; i < nnz; i += NB_GATHER) {
            float2 w = wT2[(size_t)list[i] * 256 + h];
            ax[0] += w.x; ay[0] += w.y;
        }
        g_dotp[t & 1][gb][2 * h] =
            ((ax[0] + ax[1]) + (ax[2] + ax[3])) + ((ax[4] + ax[5]) + (ax[6] + ax[7]));
        g_dotp[t & 1][gb][2 * h + 1] =
            ((ay[0] + ay[1]) + (ay[2] + ay[3])) + ((ay[4] + ay[5]) + (ay[6] + ay[7]));
    } else if (bid < NB_PARTIAL + NB_GATHER + NB_CONV1) {
        // ---- conv1: whole spike image in LDS, uniform weights ----
        if (t < 1 || t > 16) return;
        int co = bid - (NB_PARTIAL + NB_GATHER);
        const float4* __restrict__ s4 = (const float4*)g_s_in;
        float4* d4 = (float4*)sm.sim;
        for (int j = tid; j < NIN / 4; j += 256) d4[j] = s4[j];
        __syncthreads();
        float w[49];
#pragma unroll
        for (int k = 0; k < 49; ++k) w[k] = w1[co * 49 + k];
        float* __restrict__ spb = g_sp_c1[t & 1];
        for (int idx = tid; idx < D1 * D1; idx += 256) {
            int y = idx / D1, x = idx - y * D1;
            float a = 0.f;
#pragma unroll
            for (int ky = 0; ky < K1; ++ky)
#pragma unroll
                for (int kx = 0; kx < K1; ++kx)
                    a = fmaf(sm.sim[(y + ky) * DIM_IN + x + kx], w[ky * K1 + kx], a);
            int o = co * (D1 * D1) + idx;
            float mp = g_mp_c1[o] + a;
            float f = (mp >= THRES) ? 1.f : 0.f;
            g_mp_c1[o] = (mp - THRES * f) * ((f > 0.f) ? 1.f : DECAY);
            spb[o] = f;
        }
    } else if (bid < NB_PARTIAL + NB_GATHER + NB_CONV1 + NB_FIN) {
        // ---- linear1 finish for step t-1: deterministic fp64 reduction ----
        if (t < 4 || t > 19) return;
        int fb = bid - (NB_PARTIAL + NB_GATHER + NB_CONV1);  // 0..7
        int hl = tid & 63, wch = tid >> 6;
        int h = fb * 64 + hl;
        float tot;
        if (sparse) {
            int p = (t + 1) & 1;       // parity of t-1
            double s = 0.0;
            int b0 = wch * (NB_GATHER / 4);
            for (int b = b0; b < b0 + NB_GATHER / 4; ++b) s += g_dotp[p][b][h];
            sm.fin[wch * 64 + hl] = s;
            __syncthreads();
            if (wch != 0) return;
            tot = (float)((sm.fin[hl] + sm.fin[64 + hl]) +
                          (sm.fin[128 + hl] + sm.fin[192 + hl]));
        } else {
            if (wch != 0) return;
            tot = g_dot[h];
        }
        float mp = g_mp_l1[h] * DECAY + tot;
        float f = (mp >= THRES) ? 1.f : 0.f;
        g_mp_l1[h] = mp - THRES * f;
        g_sp_l1[h] = f;
    } else {
        // ---- misc: zero nnz[t&1] before reduce(t) in D2(t) increments ----
        if (tid == 0) g_nnz[t & 1] = 0;
    }
}

// ---- D2(t): reduce(t) || input(t+1) || linear2(t) ----
__global__ void __launch_bounds__(256) mega2(const float* __restrict__ wl2,
                                             const float* __restrict__ image,
                                             float* __restrict__ out,
                                             int t, int sparse) {
    int bid = blockIdx.x, tid = threadIdx.x;
    if (bid < NB_RED) {
        // ---- conv2 reduce: deterministic KC-sum, fire, decay, spike list ----
        if (t < 2 || t > 17) return;
        int i = bid * 256 + tid;
        float s = 0.f;
#pragma unroll
        for (int k = 0; k < KC; ++k) s += g_part[(size_t)k * N2 + i];
        float mp = g_mp_c2[i] + s;
        float f = (mp >= THRES) ? 1.f : 0.f;
        g_mp_c2[i] = (mp - THRES * f) * ((f > 0.f) ? 1.f : DECAY);
        if (!sparse) g_sp_c2[i] = f;
        if (f > 0.f) {
            int pos = atomicAdd(&g_nnz[t & 1], 1);
            g_list[t & 1][pos] = i;
        }
    } else if (bid == NB_RED) {
        // ---- input integrate/fire for step t+1 (reads own state only) ----
        if (t < 1 || t > 15) return;
        for (int j = tid; j < NIN; j += 256) {
            float mp = g_mp_in[j] + image[j];
            float f = (mp >= THRES) ? 1.f : 0.f;
            g_s_in[j] = f;
            g_mp_in[j] = mp - THRES * f;   // SnnInput: no decay
        }
    } else {
        // ---- linear2(t): reads sp_l1(t-1) from finish(t-1) in D1(t) ----
        if (t < 4 || t > 19) return;
        int wid = tid >> 6, lane = tid & 63;
        for (int o = wid; o < NOUT; o += 4) {
            float a = 0.f;
#pragma unroll
            for (int k = lane; k < NHID; k += 64)
                a = fmaf(wl2[o * NHID + k], g_sp_l1[k], a);
            for (int off = 32; off; off >>= 1) a += __shfl_down(a, off, 64);
            if (lane == 0) {
                float mp = g_mp_l2[o] * DECAY + a;
                float f = (mp >= THRES) ? 1.f : 0.f;
                g_mp_l2[o] = mp - THRES * f;
                out[(t + 1) * NOUT + o] = f;
            }
        }
    }
}

// Dense fallback (ws too small for wT): writes g_dot[row]; finish applies it.
__global__ void __launch_bounds__(256) linear1_dense(const float* __restrict__ wl1) {
    int row = blockIdx.x;
    const float4* __restrict__ w4 = (const float4*)(wl1 + (size_t)row * NFLAT);
    const float4* __restrict__ s4 = (const float4*)g_sp_c2;
    float acc = 0.f;
    for (int j = threadIdx.x; j < NFLAT / 4; j += 256) {
        float4 w = w4[j];
        float4 s = s4[j];
        acc += w.x * s.x + w.y * s.y + w.z * s.z + w.w * s.w;
    }
    __shared__ float red[256];
    red[threadIdx.x] = acc;
    __syncthreads();
    for (int off = 128; off >= 1; off >>= 1) {
        if (threadIdx.x < off) red[threadIdx.x] += red[threadIdx.x + off];
        __syncthreads();
    }
    if (threadIdx.x == 0) g_dot[row] = red[0];
}

extern "C" void kernel_launch(void* const* d_in, const int* in_sizes, int n_in,
                              void* d_out, int out_size, void* d_ws, size_t ws_size,
                              hipStream_t stream) {
    const float* image = (const float*)d_in[0];
    const float* w_c1 = (const float*)d_in[1];
    const float* w_c2 = (const float*)d_in[2];
    const float* w_l1 = (const float*)d_in[3];
    const float* w_l2 = (const float*)d_in[4];
    float* out = (float*)d_out;

    float* wT = (float*)d_ws;
    bool sparse = ws_size >= (size_t)NFLAT * NHID * sizeof(float);

    init_kernel<<<512, 256, 0, stream>>>(image, out);
    reshuffle_w2<<<(C2 * C1 * 49) / 256, 256, 0, stream>>>(w_c2);
    if (sparse)
        transpose_kernel<<<dim3(NFLAT / 64, NHID / 64), 256, 0, stream>>>(w_l1, wT);

    // Live ranges: conv1 1..16, conv2 2..17, gather 3..18 (finish at t+1),
    // linear2 4..19, input-role(t+1) 1..15. t=0 fully folded into init.
    for (int t = 1; t < TSTEPS; ++t) {
        mega1<<<NB1, 256, 0, stream>>>(w_c1, wT, t, sparse ? 1 : 0);
        if (!sparse && t >= 3 && t <= 18)
            linear1_dense<<<NHID, 256, 0, stream>>>(w_l1);
        mega2<<<NB2, 256, 0, stream>>>(w_l2, image, out, t, sparse ? 1 : 0);
    }
}

// Round 9
// 2094.194 us; speedup vs baseline: 3.9629x; 1.0695x over previous
//
#include <hip/hip_runtime.h>

#define TSTEPS 20
constexpr float THRES = 1.0f;
constexpr float DECAY = 0.875f;  // (2^3-1)/2^3

constexpr int DIM_IN = 64;
constexpr int NIN = DIM_IN * DIM_IN;          // 4096
constexpr int C1 = 64, K1 = 7, D1 = 58;
constexpr int N1 = C1 * D1 * D1;              // 215296
constexpr int C2 = 128, K2 = 7, D2 = 52;
constexpr int N2 = C2 * D2 * D2;              // 346112
constexpr int NFLAT = N2;
constexpr int NHID = 512;
constexpr int NOUT = 10;
constexpr int KC = 16;          // conv2 K-split chunks
constexpr int CPC = C1 / KC;    // 4 input channels per chunk
constexpr int W2R_ELEMS = 256 * 28 * 64;      // reshuffled conv2 weights

// ---- single step-dispatch D_k roles (software pipeline) ----
// D_k = partial(k) | gather(k-1) | reduce(k-1) | conv1(k) | finish(k-2)
//       | input(k+1) | linear2(k-2) | misc. Every role reads only state
//       written in D_{k-1} or earlier (buffers double/quad-slotted below).
constexpr int R_PART = 832;                    // (kc, yt, cotg)
constexpr int R_GATH = 768;
constexpr int R_RED = N2 / 256;                // 1352
constexpr int R_C1 = C1;                       // 64
constexpr int R_FIN = 8;
constexpr int B_GATH0 = R_PART;                // 832
constexpr int B_RED0 = B_GATH0 + R_GATH;       // 1600
constexpr int B_C10 = B_RED0 + R_RED;          // 2952
constexpr int B_FIN0 = B_C10 + R_C1;           // 3016
constexpr int B_INPUT = B_FIN0 + R_FIN;        // 3024
constexpr int B_LIN2 = B_INPUT + 1;            // 3025
constexpr int B_MISC = B_LIN2 + 1;             // 3026
constexpr int NBS = B_MISC + 1;                // 3027

// Persistent state (re-initialized every kernel_launch).
__device__ float g_mp_in[NIN];
__device__ float g_s_in[2][NIN];       // slot s&1: input-spikes of step s
__device__ float g_mp_c1[N1];
__device__ float g_sp_c1[2][N1];       // slot s&1: conv1 spikes of step s
__device__ float g_mp_c2[N2];
__device__ float g_sp_c2[N2];          // dense fallback path only
__device__ float g_mp_l1[NHID];
__device__ float g_sp_l1[2][NHID];     // slot s&1: linear1 spikes of step s
__device__ float g_mp_l2[NOUT];
__device__ float g_dot[2][NHID];       // dense-fallback dot, slot s&1
__device__ double g_dotp[2][R_GATH][NHID];  // gather partials (fp64, 6.3 MB)
__device__ int   g_nnz[4];             // slot s&3: conv2 spike count of step s
__device__ int   g_list[4][N2];        // slot s&3: spike indices
__device__ float g_part[2][KC * N2];   // slot s&1: conv2 K-split partials
__device__ float g_w2r[W2R_ELEMS];     // reshuffled conv2 weights

// init: zero state; fold input(0) and input(1) (image-only, deterministic):
// t=0: mp=image<1 -> no fire; t=1: mp=2*image, fire -> s_in slot 1.
__global__ void init_kernel(const float* __restrict__ image, float* __restrict__ out) {
    int i = blockIdx.x * blockDim.x + threadIdx.x;
    int stride = gridDim.x * blockDim.x;
    for (int j = i; j < NIN; j += stride) {
        float mp = 2.f * image[j];
        float f = (mp >= THRES) ? 1.f : 0.f;
        g_mp_in[j] = mp - THRES * f;
        g_s_in[1][j] = f;              // s_in(1), read by conv1(1) in D_1
        g_s_in[0][j] = 0.f;
    }
    for (int j = i; j < N1; j += stride) {
        g_mp_c1[j] = 0.f; g_sp_c1[0][j] = 0.f; g_sp_c1[1][j] = 0.f;
    }
    for (int j = i; j < N2; j += stride) { g_mp_c2[j] = 0.f; g_sp_c2[j] = 0.f; }
    if (i < NHID) {
        g_mp_l1[i] = 0.f; g_sp_l1[0][i] = 0.f; g_sp_l1[1][i] = 0.f;
        g_dot[0][i] = 0.f; g_dot[1][i] = 0.f;
    }
    if (i < NOUT) g_mp_l2[i] = 0.f;
    if (i < (TSTEPS + 1) * NOUT) out[i] = 0.f;
    if (i < 4) g_nnz[i] = 0;
}

// One-time: w_l1 [512][NFLAT] -> wT [NFLAT][512]. 64x64 tiles.
__global__ void __launch_bounds__(256) transpose_kernel(const float* __restrict__ w,
                                                        float* __restrict__ wT) {
    __shared__ float tile[64][65];
    int bx = blockIdx.x * 64;
    int by = blockIdx.y * 64;
    int tx = threadIdx.x & 63, ty = threadIdx.x >> 6;
#pragma unroll
    for (int k = 0; k < 16; ++k)
        tile[ty + 4 * k][tx] = w[(size_t)(by + ty + 4 * k) * NFLAT + bx + tx];
    __syncthreads();
#pragma unroll
    for (int k = 0; k < 16; ++k)
        wT[(size_t)(bx + ty + 4 * k) * NHID + by + tx] = tile[tx][ty + 4 * k];
}

// One-time: w_c2 [co][ci][ky][kx] -> w2r [(kc*16+cot)][c*7+ky][cl*8+kx] (kx pad 8)
__global__ void __launch_bounds__(256) reshuffle_w2(const float* __restrict__ w2) {
    int idx = blockIdx.x * 256 + threadIdx.x;
    if (idx >= C2 * C1 * 49) return;
    int co = idx / (C1 * 49);
    int rem = idx - co * (C1 * 49);
    int ci = rem / 49;
    int k = rem - ci * 49;
    int ky = k / 7, kx = k - ky * 7;
    int kc = ci >> 2, c = ci & 3;     // CPC = 4
    int cot = co >> 3, cl = co & 7;
    g_w2r[((size_t)(kc * 16 + cot) * 28 + (c * 7 + ky)) * 64 + cl * 8 + kx] = w2[idx];
}

// ---- the one dispatch per pipeline slot k (k = 1..21) ----
__global__ void __launch_bounds__(256) step_kernel(const float* __restrict__ w1,
                                                   const float* __restrict__ wT,
                                                   const float* __restrict__ wl2,
                                                   const float* __restrict__ image,
                                                   float* __restrict__ out,
                                                   int k, int sparse) {
    __shared__ union __align__(16) {
        float spk[CPC][10][58];   // 9.28 KB (partial)
        float sim[NIN];           // 16 KB  (conv1)
        double fin[256];          // 2 KB   (finish)
    } sm;
    int bid = blockIdx.x, tid = threadIdx.x;
    int wid = tid >> 6, lane = tid & 63;

    if (bid < B_GATH0) {
        // ---- conv2 partial, step s=k in [2,17]: reads sp_c1(k-1) ----
        if (k < 2 || k > 17) return;
        int kc = bid & 15;
        int tmp = bid >> 4;            // 0..51
        int cotg = tmp & 3;
        int yt = tmp >> 2;             // 0..12
        int c0 = kc * CPC, y0 = yt * 4;
        const float* __restrict__ sp = g_sp_c1[(k + 1) & 1];
        for (int e = tid; e < CPC * 10 * 58; e += 256) {
            int c = e / 580, rem = e - c * 580;
            int r = rem / 58, x = rem - r * 58;
            sm.spk[c][r][x] = sp[(c0 + c) * (D1 * D1) + (y0 + r) * D1 + x];
        }
        __syncthreads();
        int cot = __builtin_amdgcn_readfirstlane(cotg * 4 + wid);
        int co0 = cot * 8;
        float acc[8][4] = {};
        bool act = lane < D2;
        float* __restrict__ pb = g_part[k & 1];
#pragma unroll 1
        for (int c = 0; c < CPC; ++c) {
#pragma unroll
            for (int ky = 0; ky < K2; ++ky) {
                // uniform address -> s_loads into SGPRs
                const float* __restrict__ wrow =
                    g_w2r + ((size_t)(kc * 16 + cot) * 28 + (c * 7 + ky)) * 64;
                float wv[8][7];
#pragma unroll
                for (int cl = 0; cl < 8; ++cl)
#pragma unroll
                    for (int kx = 0; kx < 7; ++kx) wv[cl][kx] = wrow[cl * 8 + kx];
                if (act) {
#pragma unroll
                    for (int o = 0; o < 4; ++o) {
                        float v[7];
#pragma unroll
                        for (int kx = 0; kx < 7; ++kx) v[kx] = sm.spk[c][o + ky][lane + kx];
#pragma unroll
                        for (int kx = 0; kx < 7; ++kx)
#pragma unroll
                            for (int cl = 0; cl < 8; ++cl)
                                acc[cl][o] = fmaf(v[kx], wv[cl][kx], acc[cl][o]);
                    }
                }
            }
        }
        if (act) {
#pragma unroll
            for (int cl = 0; cl < 8; ++cl)
#pragma unroll
                for (int o = 0; o < 4; ++o)
                    pb[(size_t)kc * N2 + (co0 + cl) * (D2 * D2) + (y0 + o) * D2 + lane] =
                        acc[cl][o];
        }
    } else if (bid < B_RED0) {
        // ---- linear1 gather, step s=k-1 in [3,18]: reads list(s-1) ----
        if (!sparse || k < 4 || k > 19) return;
        int s = k - 1;
        int gb = bid - B_GATH0;
        int ps = (s - 1) & 3;
        int nnz = g_nnz[ps];
        const int* __restrict__ list = g_list[ps];
        const float2* __restrict__ wT2 = (const float2*)wT;
        int h = tid;
        double ax[8] = {}, ay[8] = {};
        int i = gb;
        for (; i + 7 * R_GATH < nnz; i += 8 * R_GATH) {
            int j[8];
#pragma unroll
            for (int u = 0; u < 8; ++u) j[u] = list[i + u * R_GATH];
#pragma unroll
            for (int u = 0; u < 8; ++u) {
                float2 w = wT2[(size_t)j[u] * 256 + h];
                ax[u] += w.x; ay[u] += w.y;
            }
        }
        for (; i < nnz; i += R_GATH) {
            float2 w = wT2[(size_t)list[i] * 256 + h];
            ax[0] += w.x; ay[0] += w.y;
        }
        g_dotp[s & 1][gb][2 * h] =
            ((ax[0] + ax[1]) + (ax[2] + ax[3])) + ((ax[4] + ax[5]) + (ax[6] + ax[7]));
        g_dotp[s & 1][gb][2 * h + 1] =
            ((ay[0] + ay[1]) + (ay[2] + ay[3])) + ((ay[4] + ay[5]) + (ay[6] + ay[7]));
    } else if (bid < B_C10) {
        // ---- conv2 reduce, step s=k-1 in [2,17]: reads part(s) ----
        if (k < 3 || k > 18) return;
        int s = k - 1;
        int i = (bid - B_RED0) * 256 + tid;
        const float* __restrict__ pb = g_part[s & 1];
        float sum = 0.f;
#pragma unroll
        for (int kk = 0; kk < KC; ++kk) sum += pb[(size_t)kk * N2 + i];
        float mp = g_mp_c2[i] + sum;
        float f = (mp >= THRES) ? 1.f : 0.f;
        g_mp_c2[i] = (mp - THRES * f) * ((f > 0.f) ? 1.f : DECAY);
        if (!sparse) g_sp_c2[i] = f;
        if (f > 0.f) {
            int pos = atomicAdd(&g_nnz[s & 3], 1);
            g_list[s & 3][pos] = i;
        }
    } else if (bid < B_FIN0) {
        // ---- conv1, step s=k in [1,16]: reads s_in(k) ----
        if (k < 1 || k > 16) return;
        int co = bid - B_C10;
        const float4* __restrict__ s4 = (const float4*)g_s_in[k & 1];
        float4* d4 = (float4*)sm.sim;
        for (int j = tid; j < NIN / 4; j += 256) d4[j] = s4[j];
        __syncthreads();
        float w[49];
#pragma unroll
        for (int kk = 0; kk < 49; ++kk) w[kk] = w1[co * 49 + kk];
        float* __restrict__ spb = g_sp_c1[k & 1];
        for (int idx = tid; idx < D1 * D1; idx += 256) {
            int y = idx / D1, x = idx - y * D1;
            float a = 0.f;
#pragma unroll
            for (int ky = 0; ky < K1; ++ky)
#pragma unroll
                for (int kx = 0; kx < K1; ++kx)
                    a = fmaf(sm.sim[(y + ky) * DIM_IN + x + kx], w[ky * K1 + kx], a);
            int o = co * (D1 * D1) + idx;
            float mp = g_mp_c1[o] + a;
            float f = (mp >= THRES) ? 1.f : 0.f;
            g_mp_c1[o] = (mp - THRES * f) * ((f > 0.f) ? 1.f : DECAY);
            spb[o] = f;
        }
    } else if (bid < B_INPUT) {
        // ---- linear1 finish, step s=k-2 in [3,18]: reads dotp(s) ----
        if (k < 5 || k > 20) return;
        int s = k - 2;
        int fb = bid - B_FIN0;             // 0..7
        int hl = tid & 63, wch = tid >> 6;
        int h = fb * 64 + hl;
        float tot;
        if (sparse) {
            int p = s & 1;
            double sum = 0.0;
            int b0 = wch * (R_GATH / 4);
            for (int b = b0; b < b0 + R_GATH / 4; ++b) sum += g_dotp[p][b][h];
            sm.fin[wch * 64 + hl] = sum;
            __syncthreads();
            if (wch != 0) return;
            tot = (float)((sm.fin[hl] + sm.fin[64 + hl]) +
                          (sm.fin[128 + hl] + sm.fin[192 + hl]));
        } else {
            if (wch != 0) return;
            tot = g_dot[s & 1][h];
        }
        float mp = g_mp_l1[h] * DECAY + tot;
        float f = (mp >= THRES) ? 1.f : 0.f;
        g_mp_l1[h] = mp - THRES * f;
        g_sp_l1[s & 1][h] = f;
    } else if (bid == B_INPUT) {
        // ---- input integrate/fire, step s=k+1 in [2,16] ----
        if (k < 1 || k > 15) return;
        int s = k + 1;
        float* __restrict__ sb = g_s_in[s & 1];
        for (int j = tid; j < NIN; j += 256) {
            float mp = g_mp_in[j] + image[j];
            float f = (mp >= THRES) ? 1.f : 0.f;
            sb[j] = f;
            g_mp_in[j] = mp - THRES * f;   // SnnInput: no decay
        }
    } else if (bid == B_LIN2) {
        // ---- linear2, step s=k-2 in [4,19]: reads sp_l1(s-1) ----
        if (k < 6 || k > 21) return;
        int s = k - 2;
        const float* __restrict__ sl = g_sp_l1[(s - 1) & 1];
        for (int o = wid; o < NOUT; o += 4) {
            float a = 0.f;
#pragma unroll
            for (int kk = lane; kk < NHID; kk += 64)
                a = fmaf(wl2[o * NHID + kk], sl[kk], a);
            for (int off = 32; off; off >>= 1) a += __shfl_down(a, off, 64);
            if (lane == 0) {
                float mp = g_mp_l2[o] * DECAY + a;
                float f = (mp >= THRES) ? 1.f : 0.f;
                g_mp_l2[o] = mp - THRES * f;
                out[(s + 1) * NOUT + o] = f;
            }
        }
    } else {
        // ---- misc: zero nnz[k&3] for reduce(k) (runs in D_{k+1}) ----
        if (k < 2 || k > 17) return;
        if (tid == 0) g_nnz[k & 3] = 0;
    }
}

// Dense fallback (ws too small for wT): writes g_dot[slot]; finish applies it.
__global__ void __launch_bounds__(256) linear1_dense(const float* __restrict__ wl1,
                                                     int slot) {
    int row = blockIdx.x;
    const float4* __restrict__ w4 = (const float4*)(wl1 + (size_t)row * NFLAT);
    const float4* __restrict__ s4 = (const float4*)g_sp_c2;
    float acc = 0.f;
    for (int j = threadIdx.x; j < NFLAT / 4; j += 256) {
        float4 w = w4[j];
        float4 s = s4[j];
        acc += w.x * s.x + w.y * s.y + w.z * s.z + w.w * s.w;
    }
    __shared__ float red[256];
    red[threadIdx.x] = acc;
    __syncthreads();
    for (int off = 128; off >= 1; off >>= 1) {
        if (threadIdx.x < off) red[threadIdx.x] += red[threadIdx.x + off];
        __syncthreads();
    }
    if (threadIdx.x == 0) g_dot[slot][row] = red[0];
}

extern "C" void kernel_launch(void* const* d_in, const int* in_sizes, int n_in,
                              void* d_out, int out_size, void* d_ws, size_t ws_size,
                              hipStream_t stream) {
    const float* image = (const float*)d_in[0];
    const float* w_c1 = (const float*)d_in[1];
    const float* w_c2 = (const float*)d_in[2];
    const float* w_l1 = (const float*)d_in[3];
    const float* w_l2 = (const float*)d_in[4];
    float* out = (float*)d_out;

    float* wT = (float*)d_ws;
    bool sparse = ws_size >= (size_t)NFLAT * NHID * sizeof(float);

    init_kernel<<<512, 256, 0, stream>>>(image, out);
    reshuffle_w2<<<(C2 * C1 * 49) / 256, 256, 0, stream>>>(w_c2);
    if (sparse)
        transpose_kernel<<<dim3(NFLAT / 64, NHID / 64), 256, 0, stream>>>(w_l1, wT);

    // Pipeline: D_k = partial(k)|gather(k-1)|reduce(k-1)|conv1(k)|finish(k-2)
    //                 |input(k+1)|linear2(k-2). k = 1..21.
    for (int k = 1; k <= 21; ++k) {
        step_kernel<<<NBS, 256, 0, stream>>>(w_c1, wT, w_l2, image, out, k,
                                             sparse ? 1 : 0);
        // dense fallback: linear1_dense(s=k) after D_k (reads sp_c2(k-1)),
        // consumed by finish(k) in D_{k+2}.
        if (!sparse && k >= 3 && k <= 18)
            linear1_dense<<<NHID, 256, 0, stream>>>(w_l1, k & 1);
    }
}

// Round 10
// 1710.221 us; speedup vs baseline: 4.8526x; 1.2245x over previous
//
#include <hip/hip_runtime.h>

#define TSTEPS 20
constexpr float THRES = 1.0f;
constexpr float DECAY = 0.875f;  // (2^3-1)/2^3

constexpr int DIM_IN = 64;
constexpr int NIN = DIM_IN * DIM_IN;          // 4096
constexpr int C1 = 64, K1 = 7, D1 = 58;
constexpr int N1 = C1 * D1 * D1;              // 215296
constexpr int C2 = 128, K2 = 7, D2 = 52;
constexpr int N2 = C2 * D2 * D2;              // 346112
constexpr int NFLAT = N2;
constexpr int NHID = 512;
constexpr int NOUT = 10;
constexpr int KC = 16;          // conv2 K-split chunks
constexpr int CPC = C1 / KC;    // 4 input channels per chunk
constexpr int W2R_ELEMS = 256 * 28 * 64;      // reshuffled conv2 weights

// ---- single step-dispatch D_k roles (software pipeline) ----
constexpr int R_PART = 832;                    // (kc, yt, cotg)
constexpr int R_GATH = 768;
constexpr int R_RED = N2 / 256;                // 1352
constexpr int R_C1 = C1;                       // 64
constexpr int R_FIN = 8;
constexpr int B_GATH0 = R_PART;                // 832
constexpr int B_RED0 = B_GATH0 + R_GATH;       // 1600
constexpr int B_C10 = B_RED0 + R_RED;          // 2952
constexpr int B_FIN0 = B_C10 + R_C1;           // 3016
constexpr int B_INPUT = B_FIN0 + R_FIN;        // 3024
constexpr int B_LIN2 = B_INPUT + 1;            // 3025
constexpr int B_MISC = B_LIN2 + 1;             // 3026
constexpr int NBS = B_MISC + 1;                // 3027

// Persistent state (re-initialized every kernel_launch).
__device__ float g_mp_in[NIN];
__device__ float g_s_in[2][NIN];       // slot s&1: input-spikes of step s
__device__ float g_mp_c1[N1];
__device__ float g_sp_c1[2][N1];       // slot s&1: conv1 spikes of step s
__device__ float g_mp_c2[N2];
__device__ float g_sp_c2[N2];          // dense fallback path only
__device__ float g_mp_l1[NHID];
__device__ float g_sp_l1[2][NHID];     // slot s&1: linear1 spikes of step s
__device__ float g_mp_l2[NOUT];
__device__ float g_dot[2][NHID];       // dense-fallback dot, slot s&1
__device__ double g_dotp[2][R_GATH][NHID];  // gather partials (fp64, 6.3 MB)
__device__ int   g_nnz[4];             // slot s&3: conv2 spike count of step s
__device__ int   g_list[4][N2];        // slot s&3: spike indices
__device__ float g_part[2][KC * N2];   // slot s&1: conv2 K-split partials
__device__ float g_w2r[W2R_ELEMS];     // reshuffled conv2 weights

// init: zero state; fold input(0) and input(1) (image-only, deterministic):
// t=0: mp=image<1 -> no fire; t=1: mp=2*image, fire -> s_in slot 1.
__global__ void init_kernel(const float* __restrict__ image, float* __restrict__ out) {
    int i = blockIdx.x * blockDim.x + threadIdx.x;
    int stride = gridDim.x * blockDim.x;
    for (int j = i; j < NIN; j += stride) {
        float mp = 2.f * image[j];
        float f = (mp >= THRES) ? 1.f : 0.f;
        g_mp_in[j] = mp - THRES * f;
        g_s_in[1][j] = f;              // s_in(1), read by conv1(1) in D_1
        g_s_in[0][j] = 0.f;
    }
    for (int j = i; j < N1; j += stride) {
        g_mp_c1[j] = 0.f; g_sp_c1[0][j] = 0.f; g_sp_c1[1][j] = 0.f;
    }
    for (int j = i; j < N2; j += stride) { g_mp_c2[j] = 0.f; g_sp_c2[j] = 0.f; }
    if (i < NHID) {
        g_mp_l1[i] = 0.f; g_sp_l1[0][i] = 0.f; g_sp_l1[1][i] = 0.f;
        g_dot[0][i] = 0.f; g_dot[1][i] = 0.f;
    }
    if (i < NOUT) g_mp_l2[i] = 0.f;
    if (i < (TSTEPS + 1) * NOUT) out[i] = 0.f;
    if (i < 4) g_nnz[i] = 0;
}

// One-time: w_l1 [512][NFLAT] -> wT [NFLAT][512]. 64x64 tiles.
__global__ void __launch_bounds__(256) transpose_kernel(const float* __restrict__ w,
                                                        float* __restrict__ wT) {
    __shared__ float tile[64][65];
    int bx = blockIdx.x * 64;
    int by = blockIdx.y * 64;
    int tx = threadIdx.x & 63, ty = threadIdx.x >> 6;
#pragma unroll
    for (int k = 0; k < 16; ++k)
        tile[ty + 4 * k][tx] = w[(size_t)(by + ty + 4 * k) * NFLAT + bx + tx];
    __syncthreads();
#pragma unroll
    for (int k = 0; k < 16; ++k)
        wT[(size_t)(bx + ty + 4 * k) * NHID + by + tx] = tile[tx][ty + 4 * k];
}

// One-time: w_c2 [co][ci][ky][kx] -> w2r [(kc*16+cot)][c*7+ky][cl*8+kx] (kx pad 8)
__global__ void __launch_bounds__(256) reshuffle_w2(const float* __restrict__ w2) {
    int idx = blockIdx.x * 256 + threadIdx.x;
    if (idx >= C2 * C1 * 49) return;
    int co = idx / (C1 * 49);
    int rem = idx - co * (C1 * 49);
    int ci = rem / 49;
    int k = rem - ci * 49;
    int ky = k / 7, kx = k - ky * 7;
    int kc = ci >> 2, c = ci & 3;     // CPC = 4
    int cot = co >> 3, cl = co & 7;
    g_w2r[((size_t)(kc * 16 + cot) * 28 + (c * 7 + ky)) * 64 + cl * 8 + kx] = w2[idx];
}

// ---- the one dispatch per pipeline slot k (k = 1..21) ----
// D_k = partial(k)|gather(k-1)|reduce(k-1)|conv1(k)|finish(k-2)|input(k+1)
//       |linear2(k-2)|misc. Every role reads only prior-dispatch state.
__global__ void __launch_bounds__(256) step_kernel(const float* __restrict__ w1,
                                                   const float* __restrict__ wT,
                                                   const float* __restrict__ wl2,
                                                   const float* __restrict__ image,
                                                   float* __restrict__ out,
                                                   int k, int sparse) {
    __shared__ union __align__(16) {
        float spk[CPC][10][58];           // 9.28 KB (partial)
        float sim[NIN];                   // 16 KB  (conv1)
        double fin[256];                  // 2 KB   (finish)
        struct { int wcnt[4]; int base; } red;  // (reduce list-build)
    } sm;
    int bid = blockIdx.x, tid = threadIdx.x;
    int wid = tid >> 6, lane = tid & 63;

    if (bid < B_GATH0) {
        // ---- conv2 partial, step s=k in [2,17]: reads sp_c1(k-1) ----
        if (k < 2 || k > 17) return;
        int kc = bid & 15;
        int tmp = bid >> 4;            // 0..51
        int cotg = tmp & 3;
        int yt = tmp >> 2;             // 0..12
        int c0 = kc * CPC, y0 = yt * 4;
        const float* __restrict__ sp = g_sp_c1[(k + 1) & 1];
        for (int e = tid; e < CPC * 10 * 58; e += 256) {
            int c = e / 580, rem = e - c * 580;
            int r = rem / 58, x = rem - r * 58;
            sm.spk[c][r][x] = sp[(c0 + c) * (D1 * D1) + (y0 + r) * D1 + x];
        }
        __syncthreads();
        int cot = __builtin_amdgcn_readfirstlane(cotg * 4 + wid);
        int co0 = cot * 8;
        float acc[8][4] = {};
        bool act = lane < D2;
        float* __restrict__ pb = g_part[k & 1];
#pragma unroll 1
        for (int c = 0; c < CPC; ++c) {
#pragma unroll
            for (int ky = 0; ky < K2; ++ky) {
                // hoist spike regs out of the cl loop (28 ds_reads / 224 FMA)
                float v[4][7];
                if (act) {
#pragma unroll
                    for (int o = 0; o < 4; ++o)
#pragma unroll
                        for (int kx = 0; kx < 7; ++kx)
                            v[o][kx] = sm.spk[c][o + ky][lane + kx];
                }
                const float* __restrict__ wrow =
                    g_w2r + ((size_t)(kc * 16 + cot) * 28 + (c * 7 + ky)) * 64;
#pragma unroll
                for (int cl = 0; cl < 8; ++cl) {
                    float wv[7];   // 7 live scalar weights at a time
#pragma unroll
                    for (int kx = 0; kx < 7; ++kx) wv[kx] = wrow[cl * 8 + kx];
                    if (act) {
#pragma unroll
                        for (int o = 0; o < 4; ++o)
#pragma unroll
                            for (int kx = 0; kx < 7; ++kx)
                                acc[cl][o] = fmaf(v[o][kx], wv[kx], acc[cl][o]);
                    }
                }
            }
        }
        if (act) {
#pragma unroll
            for (int cl = 0; cl < 8; ++cl)
#pragma unroll
                for (int o = 0; o < 4; ++o)
                    pb[(size_t)kc * N2 + (co0 + cl) * (D2 * D2) + (y0 + o) * D2 + lane] =
                        acc[cl][o];
        }
    } else if (bid < B_RED0) {
        // ---- linear1 gather, step s=k-1 in [3,18]: reads list(s-1) ----
        if (!sparse || k < 4 || k > 19) return;
        int s = k - 1;
        int gb = bid - B_GATH0;
        int ps = (s - 1) & 3;
        int nnz = g_nnz[ps];
        const int* __restrict__ list = g_list[ps];
        const float2* __restrict__ wT2 = (const float2*)wT;
        int h = tid;
        double ax[8] = {}, ay[8] = {};
        int i = gb;
        for (; i + 7 * R_GATH < nnz; i += 8 * R_GATH) {
            int j[8];
#pragma unroll
            for (int u = 0; u < 8; ++u) j[u] = list[i + u * R_GATH];
#pragma unroll
            for (int u = 0; u < 8; ++u) {
                float2 w = wT2[(size_t)j[u] * 256 + h];
                ax[u] += w.x; ay[u] += w.y;
            }
        }
        for (; i < nnz; i += R_GATH) {
            float2 w = wT2[(size_t)list[i] * 256 + h];
            ax[0] += w.x; ay[0] += w.y;
        }
        g_dotp[s & 1][gb][2 * h] =
            ((ax[0] + ax[1]) + (ax[2] + ax[3])) + ((ax[4] + ax[5]) + (ax[6] + ax[7]));
        g_dotp[s & 1][gb][2 * h + 1] =
            ((ay[0] + ay[1]) + (ay[2] + ay[3])) + ((ay[4] + ay[5]) + (ay[6] + ay[7]));
    } else if (bid < B_C10) {
        // ---- conv2 reduce, step s=k-1 in [2,17]: reads part(s) ----
        // Block-aggregated spike-list build: ballot -> LDS wave scan -> ONE
        // atomicAdd per spiking block (vs per-wave: 4x fewer same-line
        // atomics, coalesced list writes).
        if (k < 3 || k > 18) return;
        int s = k - 1;
        int i = (bid - B_RED0) * 256 + tid;
        const float* __restrict__ pb = g_part[s & 1];
        float sum = 0.f;
#pragma unroll
        for (int kk = 0; kk < KC; ++kk) sum += pb[(size_t)kk * N2 + i];
        float mp = g_mp_c2[i] + sum;
        float f = (mp >= THRES) ? 1.f : 0.f;
        g_mp_c2[i] = (mp - THRES * f) * ((f > 0.f) ? 1.f : DECAY);
        if (!sparse) g_sp_c2[i] = f;
        bool spike = f > 0.f;
        unsigned long long m = __ballot(spike);
        int lpre = __popcll(m & ((1ull << lane) - 1));
        if (lane == 0) sm.red.wcnt[wid] = __popcll(m);
        __syncthreads();
        int w0 = sm.red.wcnt[0], w1c = sm.red.wcnt[1],
            w2c = sm.red.wcnt[2], w3c = sm.red.wcnt[3];
        int total = w0 + w1c + w2c + w3c;
        if (tid == 0 && total > 0)
            sm.red.base = atomicAdd(&g_nnz[s & 3], total);
        __syncthreads();
        if (spike) {
            int woff = (wid > 0 ? w0 : 0) + (wid > 1 ? w1c : 0) + (wid > 2 ? w2c : 0);
            g_list[s & 3][sm.red.base + woff + lpre] = i;
        }
    } else if (bid < B_FIN0) {
        // ---- conv1, step s=k in [1,16]: reads s_in(k) ----
        if (k < 1 || k > 16) return;
        int co = bid - B_C10;
        const float4* __restrict__ s4 = (const float4*)g_s_in[k & 1];
        float4* d4 = (float4*)sm.sim;
        for (int j = tid; j < NIN / 4; j += 256) d4[j] = s4[j];
        __syncthreads();
        float w[49];
#pragma unroll
        for (int kk = 0; kk < 49; ++kk) w[kk] = w1[co * 49 + kk];
        float* __restrict__ spb = g_sp_c1[k & 1];
        for (int idx = tid; idx < D1 * D1; idx += 256) {
            int y = idx / D1, x = idx - y * D1;
            float a = 0.f;
#pragma unroll
            for (int ky = 0; ky < K1; ++ky)
#pragma unroll
                for (int kx = 0; kx < K1; ++kx)
                    a = fmaf(sm.sim[(y + ky) * DIM_IN + x + kx], w[ky * K1 + kx], a);
            int o = co * (D1 * D1) + idx;
            float mp = g_mp_c1[o] + a;
            float f = (mp >= THRES) ? 1.f : 0.f;
            g_mp_c1[o] = (mp - THRES * f) * ((f > 0.f) ? 1.f : DECAY);
            spb[o] = f;
        }
    } else if (bid < B_INPUT) {
        // ---- linear1 finish, step s=k-2 in [3,18]: reads dotp(s) ----
        if (k < 5 || k > 20) return;
        int s = k - 2;
        int fb = bid - B_FIN0;             // 0..7
        int hl = tid & 63, wch = tid >> 6;
        int h = fb * 64 + hl;
        float tot;
        if (sparse) {
            int p = s & 1;
            double sum = 0.0;
            int b0 = wch * (R_GATH / 4);
            for (int b = b0; b < b0 + R_GATH / 4; ++b) sum += g_dotp[p][b][h];
            sm.fin[wch * 64 + hl] = sum;
            __syncthreads();
            if (wch != 0) return;
            tot = (float)((sm.fin[hl] + sm.fin[64 + hl]) +
                          (sm.fin[128 + hl] + sm.fin[192 + hl]));
        } else {
            if (wch != 0) return;
            tot = g_dot[s & 1][h];
        }
        float mp = g_mp_l1[h] * DECAY + tot;
        float f = (mp >= THRES) ? 1.f : 0.f;
        g_mp_l1[h] = mp - THRES * f;
        g_sp_l1[s & 1][h] = f;
    } else if (bid == B_INPUT) {
        // ---- input integrate/fire, step s=k+1 in [2,16] ----
        if (k < 1 || k > 15) return;
        int s = k + 1;
        float* __restrict__ sb = g_s_in[s & 1];
        for (int j = tid; j < NIN; j += 256) {
            float mp = g_mp_in[j] + image[j];
            float f = (mp >= THRES) ? 1.f : 0.f;
            sb[j] = f;
            g_mp_in[j] = mp - THRES * f;   // SnnInput: no decay
        }
    } else if (bid == B_LIN2) {
        // ---- linear2, step s=k-2 in [4,19]: reads sp_l1(s-1) ----
        if (k < 6 || k > 21) return;
        int s = k - 2;
        const float* __restrict__ sl = g_sp_l1[(s - 1) & 1];
        for (int o = wid; o < NOUT; o += 4) {
            float a = 0.f;
#pragma unroll
            for (int kk = lane; kk < NHID; kk += 64)
                a = fmaf(wl2[o * NHID + kk], sl[kk], a);
            for (int off = 32; off; off >>= 1) a += __shfl_down(a, off, 64);
            if (lane == 0) {
                float mp = g_mp_l2[o] * DECAY + a;
                float f = (mp >= THRES) ? 1.f : 0.f;
                g_mp_l2[o] = mp - THRES * f;
                out[(s + 1) * NOUT + o] = f;
            }
        }
    } else {
        // ---- misc: zero nnz[k&3] for reduce(k) (runs in D_{k+1}) ----
        if (k < 2 || k > 17) return;
        if (tid == 0) g_nnz[k & 3] = 0;
    }
}

// Dense fallback (ws too small for wT): writes g_dot[slot]; finish applies it.
__global__ void __launch_bounds__(256) linear1_dense(const float* __restrict__ wl1,
                                                     int slot) {
    int row = blockIdx.x;
    const float4* __restrict__ w4 = (const float4*)(wl1 + (size_t)row * NFLAT);
    const float4* __restrict__ s4 = (const float4*)g_sp_c2;
    float acc = 0.f;
    for (int j = threadIdx.x; j < NFLAT / 4; j += 256) {
        float4 w = w4[j];
        float4 s = s4[j];
        acc += w.x * s.x + w.y * s.y + w.z * s.z + w.w * s.w;
    }
    __shared__ float red[256];
    red[threadIdx.x] = acc;
    __syncthreads();
    for (int off = 128; off >= 1; off >>= 1) {
        if (threadIdx.x < off) red[threadIdx.x] += red[threadIdx.x + off];
        __syncthreads();
    }
    if (threadIdx.x == 0) g_dot[slot][row] = red[0];
}

extern "C" void kernel_launch(void* const* d_in, const int* in_sizes, int n_in,
                              void* d_out, int out_size, void* d_ws, size_t ws_size,
                              hipStream_t stream) {
    const float* image = (const float*)d_in[0];
    const float* w_c1 = (const float*)d_in[1];
    const float* w_c2 = (const float*)d_in[2];
    const float* w_l1 = (const float*)d_in[3];
    const float* w_l2 = (const float*)d_in[4];
    float* out = (float*)d_out;

    float* wT = (float*)d_ws;
    bool sparse = ws_size >= (size_t)NFLAT * NHID * sizeof(float);

    init_kernel<<<512, 256, 0, stream>>>(image, out);
    reshuffle_w2<<<(C2 * C1 * 49) / 256, 256, 0, stream>>>(w_c2);
    if (sparse)
        transpose_kernel<<<dim3(NFLAT / 64, NHID / 64), 256, 0, stream>>>(w_l1, wT);

    // Pipeline: D_k = partial(k)|gather(k-1)|reduce(k-1)|conv1(k)|finish(k-2)
    //                 |input(k+1)|linear2(k-2). k = 1..21.
    for (int k = 1; k <= 21; ++k) {
        step_kernel<<<NBS, 256, 0, stream>>>(w_c1, wT, w_l2, image, out, k,
                                             sparse ? 1 : 0);
        if (!sparse && k >= 3 && k <= 18)
            linear1_dense<<<NHID, 256, 0, stream>>>(w_l1, k & 1);
    }
}